// Round 5
// baseline (1063.716 us; speedup 1.0000x reference)
//
#include <hip/hip_runtime.h>
#include <hip/hip_bf16.h>

#define N_    64
#define CIN   128
#define COUT  256
#define T_    128
#define V_    25
#define TOUT  64
#define VOUT  13
#define EPS_  1e-5f

typedef __hip_bfloat16 bf16;
typedef __attribute__((ext_vector_type(8))) short short8x;
typedef __attribute__((ext_vector_type(4))) float f32x4;

__device__ __forceinline__ float ldv(const bf16* p)  { return __bfloat162float(*p); }
__device__ __forceinline__ float ldv(const float* p) { return *p; }
__device__ __forceinline__ void  stv(bf16* p, float v)  { *p = __float2bfloat16(v); }
__device__ __forceinline__ void  stv(float* p, float v) { *p = v; }

__device__ __forceinline__ unsigned bf16rne(float f) {
    unsigned u = __float_as_uint(f);
    return (u + 0x7FFFu + ((u >> 16) & 1u)) >> 16;
}

// vectorized 4-element load -> 4 floats
__device__ __forceinline__ void load4(const float* p, float& a, float& b, float& c, float& d) {
    float4 v = *reinterpret_cast<const float4*>(p);
    a = v.x; b = v.y; c = v.z; d = v.w;
}
__device__ __forceinline__ void load4(const bf16* p, float& a, float& b, float& c, float& d) {
    ushort4 u = *reinterpret_cast<const ushort4*>(p);
    a = __uint_as_float((unsigned)u.x << 16);
    b = __uint_as_float((unsigned)u.y << 16);
    c = __uint_as_float((unsigned)u.z << 16);
    d = __uint_as_float((unsigned)u.w << 16);
}

// Reduce (s, ss) across a 256-thread block; valid in thread 0 afterwards.
__device__ __forceinline__ void blockReduce2(float& s, float& ss) {
    __shared__ float ls[4], lss[4];
    int lane = threadIdx.x & 63, wid = threadIdx.x >> 6;
#pragma unroll
    for (int o = 32; o > 0; o >>= 1) {
        s  += __shfl_down(s, o, 64);
        ss += __shfl_down(ss, o, 64);
    }
    if (lane == 0) { ls[wid] = s; lss[wid] = ss; }
    __syncthreads();
    if (threadIdx.x == 0) {
        s  = ls[0] + ls[1] + ls[2] + ls[3];
        ss = lss[0] + lss[1] + lss[2] + lss[3];
    }
}

// ---- dtype detector + zero-init of bn1 partial sums ----
__global__ void detect_k(const unsigned short* __restrict__ xr, int* flag,
                         float* __restrict__ s1, float* __restrict__ q1) {
    if (threadIdx.x < CIN) { s1[threadIdx.x] = 0.f; q1[threadIdx.x] = 0.f; }
    __shared__ int cnt;
    if (threadIdx.x == 0) cnt = 0;
    __syncthreads();
    int c = 0;
    for (int i = threadIdx.x; i < 8192; i += 256) {
        int e = (xr[i] >> 7) & 0xFF;
        if (e >= 192) c++;
    }
    atomicAdd(&cnt, c);
    __syncthreads();
    if (threadIdx.x == 0) flag[0] = (cnt > 0) ? 1 : 0;
}

// ---- MODE1 weight prepass: convert to fp32, layout [ci][co][9] ----
__global__ __launch_bounds__(256) void wcvt_k(const int* __restrict__ flag,
                                              const float* __restrict__ wgt,
                                              float* __restrict__ w32) {
    if (flag[0] != 1) return;
    int total = COUT * CIN * 9;
    for (int i = blockIdx.x * 256 + threadIdx.x; i < total; i += gridDim.x * 256) {
        int co = i / (CIN * 9);
        int r  = i - co * (CIN * 9);
        int ci = r / 9;
        int k  = r - ci * 9;
        w32[((size_t)ci * COUT + co) * 9 + k] = wgt[i];
    }
}

// ---- MODE0 weight prepass: duplicate bf16 at k=(2ci, 2ci+1), layout [tap][co][k] ----
// w2u[(tap*256 + co)*128 + ci] = bits | (bits<<16)
__global__ __launch_bounds__(256) void wcvt2_k(const int* __restrict__ flag,
                                               const unsigned short* __restrict__ wgt,
                                               unsigned* __restrict__ w2u) {
    if (flag[0] != 0) return;
    int total = COUT * CIN * 9;
    for (int i = blockIdx.x * 256 + threadIdx.x; i < total; i += gridDim.x * 256) {
        int co = i / (CIN * 9);
        int r  = i - co * (CIN * 9);
        int ci = r / 9;
        int k9 = r - ci * 9;
        unsigned wb = wgt[i];
        w2u[((size_t)k9 * COUT + co) * (CIN) + ci] = wb | (wb << 16);
    }
}

// ---- BN1 partial sums: grid (CIN, 4), vectorized loads, atomic accumulate ----
template<int MODE, typename DT>
__global__ __launch_bounds__(256) void bn1_k(const int* __restrict__ flag,
                                             const DT* __restrict__ x,
                                             float* __restrict__ s1, float* __restrict__ q1) {
    if (flag[0] != MODE) return;
    const int c  = blockIdx.x;
    const int n0 = blockIdx.y * (N_ / 4);
    float s = 0.f, ss = 0.f;
    for (int idx = threadIdx.x; idx < (N_ / 4) * 800; idx += 256) {
        int n = n0 + idx / 800;
        int q = idx - (idx / 800) * 800;
        const DT* xp = x + ((size_t)n * CIN + c) * (T_ * V_) + q * 4;
        float v0, v1, v2, v3;
        load4(xp, v0, v1, v2, v3);
        s  += (v0 + v1) + (v2 + v3);
        ss += (v0 * v0 + v1 * v1) + (v2 * v2 + v3 * v3);
    }
    blockReduce2(s, ss);
    if (threadIdx.x == 0) { atomicAdd(&s1[c], s); atomicAdd(&q1[c], ss); }
}

// ---- BN1 finalize: a1,b1 from partial sums ----
template<int MODE, typename DT>
__global__ void bn1fin_k(const int* __restrict__ flag,
                         const DT* __restrict__ gamma, const DT* __restrict__ beta,
                         const float* __restrict__ s1, const float* __restrict__ q1,
                         float* __restrict__ a1, float* __restrict__ b1) {
    if (flag[0] != MODE) return;
    int c = threadIdx.x;  // 128 threads
    float cnt = (float)(N_ * T_ * V_);
    float mean = s1[c] / cnt;
    float var = q1[c] / cnt - mean * mean;
    float a = ldv(&gamma[c]) * rsqrtf(var + EPS_);
    a1[c] = a;
    b1[c] = ldv(&beta[c]) - mean * a;
}

// ================= MODE 0: MFMA conv =================
// Block: (tg = 4 'to', n), 256 thr = 4 waves. Wave w owns co [w*64, w*64+64)
// (4 M-tiles of 16) x all 4 to (4 N-tiles; N = 16 vo slots, 13 valid).
// K per tap = 2*CIN (hi/lo interleaved: k = 2ci+p); W duplicated at both k.
// LDS: packed u32 (hi | lo<<16) [lt 9][vv 27][ci 36pad] = 35 KB.
// Per 32-ci chunk per wave: 72 A 16B global loads (L1-hot), 72 ds_read_b128,
// 288 MFMA (16x16x32 bf16).
__global__ __launch_bounds__(256) void conv_mfma_k(const int* __restrict__ flag,
                                                   const bf16* __restrict__ x,
                                                   const unsigned* __restrict__ w2u,
                                                   const bf16* __restrict__ bias,
                                                   const bf16* __restrict__ s_in,
                                                   const float* __restrict__ a1,
                                                   const float* __restrict__ b1,
                                                   bf16* __restrict__ y) {
    if (flag[0] != 0) return;
    __shared__ __align__(16) unsigned shp[9 * 27 * 36];
    const int tg    = blockIdx.x;       // 0..15
    const int n     = blockIdx.y;       // 0..63
    const int tid   = threadIdx.x;
    const int wv    = tid >> 6;         // wave id -> co block
    const int lane  = tid & 63;
    const int khi   = lane >> 4;        // 0..3 : k-group
    const int ln16  = lane & 15;        // m (co) for A; n (vo) for B/C
    const int wbase = wv * 64;
    const int tbase = 8 * tg - 1;       // t_in = tbase + lt, lt in [0,9)

    const short8x* w2v = reinterpret_cast<const short8x*>(w2u);
    const short8x* shv = reinterpret_cast<const short8x*>(shp);

    f32x4 acc[4][4];
#pragma unroll
    for (int ct = 0; ct < 4; ct++)
#pragma unroll
        for (int tt = 0; tt < 4; tt++) acc[ct][tt] = (f32x4){0.f, 0.f, 0.f, 0.f};

#pragma unroll 1
    for (int cc = 0; cc < 4; cc++) {    // ci chunks of 32
        __syncthreads();
        // ---- stage shift_in + BN1 chunk, bf16 hi/lo packed ----
        for (int e = tid; e < 32 * 9 * 27; e += 256) {
            int vv = e % 27;
            int r0 = e / 27;
            int lt = r0 % 9;
            int ci = r0 / 9;
            int gci  = cc * 32 + ci;
            int t_in = tbase + lt;
            int v_in = vv - 1;
            float hv = 0.f;
            if (t_in >= 0 && t_in < T_ && v_in >= 0 && v_in < V_) {
                float s = ldv(&s_in[gci]);
                float tsrc = (float)t_in + s;
                float f0 = floorf(tsrc);
                float frac = tsrc - f0;
                int i0 = (int)f0;
                int i1 = i0 + 1;
                float w0 = (i0 >= 0 && i0 < T_) ? (1.f - frac) : 0.f;
                float w1 = (i1 >= 0 && i1 < T_) ? frac : 0.f;
                int i0c = min(max(i0, 0), T_ - 1);
                int i1c = min(max(i1, 0), T_ - 1);
                const bf16* xc = x + ((size_t)n * CIN + gci) * (T_ * V_);
                float xv = w0 * ldv(&xc[i0c * V_ + v_in]) + w1 * ldv(&xc[i1c * V_ + v_in]);
                hv = a1[gci] * xv + b1[gci] * (w0 + w1);
            }
            unsigned hb = bf16rne(hv);
            float hif = __uint_as_float(hb << 16);
            unsigned lb = bf16rne(hv - hif);
            shp[(lt * 27 + vv) * 36 + ci] = hb | (lb << 16);
        }
        __syncthreads();

        // ---- MFMA over 9 taps ----
#pragma unroll 1
        for (int kt = 0; kt < 3; kt++) {
#pragma unroll 1
            for (int kv = 0; kv < 3; kv++) {
                const int tap = kt * 3 + kv;
                // A fragments: 4 co-tiles x 2 k-steps (16B each, wave-gather, L1-hot)
                short8x af[4][2];
#pragma unroll
                for (int ct = 0; ct < 4; ct++) {
                    int cobase = (tap * COUT + wbase + ct * 16 + ln16) * 32 + cc * 8 + khi;
#pragma unroll
                    for (int ks = 0; ks < 2; ks++)
                        af[ct][ks] = w2v[cobase + ks * 4];
                }
                const int vvc = min(2 * ln16 + kv, 26);
#pragma unroll
                for (int tt = 0; tt < 4; tt++) {
                    const int lt = 2 * tt + kt;
                    const int rb = (lt * 27 + vvc) * 9 + khi;
                    short8x b0 = shv[rb];
                    short8x b1 = shv[rb + 4];
#pragma unroll
                    for (int ct = 0; ct < 4; ct++) {
                        acc[ct][tt] = __builtin_amdgcn_mfma_f32_16x16x32_bf16(af[ct][0], b0, acc[ct][tt], 0, 0, 0);
                        acc[ct][tt] = __builtin_amdgcn_mfma_f32_16x16x32_bf16(af[ct][1], b1, acc[ct][tt], 0, 0, 0);
                    }
                }
            }
        }
    }

    // ---- epilogue: bias + relu + store (C: col=lane&15 -> vo, row=khi*4+r -> co) ----
    if (ln16 < VOUT) {
#pragma unroll
        for (int ct = 0; ct < 4; ct++) {
#pragma unroll
            for (int r = 0; r < 4; r++) {
                const int co = wbase + ct * 16 + khi * 4 + r;
                const float bi = ldv(&bias[co]);
#pragma unroll
                for (int tt = 0; tt < 4; tt++) {
                    const int to = tg * 4 + tt;
                    bf16* yp = y + (((size_t)n * COUT + co) * TOUT + to) * VOUT;
                    stv(&yp[ln16], fmaxf(acc[ct][tt][r] + bi, 0.f));
                }
            }
        }
    }
}

// ================= MODE 1: fp32 VALU conv (unchanged from round 4) =================
#define CI_CHUNK 16
#define LROWS    9
__global__ __launch_bounds__(256) void conv_f32_k(const int* __restrict__ flag,
                                                  const float* __restrict__ x,
                                                  const float* __restrict__ w32,
                                                  const float* __restrict__ bias,
                                                  const float* __restrict__ s_in,
                                                  const float* __restrict__ a1,
                                                  const float* __restrict__ b1,
                                                  float* __restrict__ y) {
    if (flag[0] != 1) return;
    __shared__ __align__(16) float sh[CI_CHUNK][LROWS][28];
    const int tg   = blockIdx.x;
    const int cog  = blockIdx.y;
    const int n    = blockIdx.z;
    const int tid  = threadIdx.x;
    const int wid  = tid >> 6;
    const int lane = tid & 63;
    const int tq   = lane >> 4;
    const int vo   = lane & 15;
    const int voc  = min(vo, 12);
    const int co_w = __builtin_amdgcn_readfirstlane(cog * 64 + wid * 16);
    const int to   = tg * 4 + tq;
    const int tbase = 8 * tg - 1;

    float acc[16];
#pragma unroll
    for (int j = 0; j < 16; j++) acc[j] = 0.f;

#pragma unroll 1
    for (int cc = 0; cc < CIN; cc += CI_CHUNK) {
        for (int e = tid; e < CI_CHUNK * LROWS * 27; e += 256) {
            int ci = e / (LROWS * 27);
            int r0 = e - ci * (LROWS * 27);
            int lt = r0 / 27;
            int vv = r0 - lt * 27;
            int t_in = tbase + lt;
            int v_in = vv - 1;
            float hv = 0.f;
            if (t_in >= 0 && t_in < T_ && v_in >= 0 && v_in < V_) {
                int gci = cc + ci;
                float s = s_in[gci];
                float tsrc = (float)t_in + s;
                float f0 = floorf(tsrc);
                float frac = tsrc - f0;
                int i0 = (int)f0;
                int i1 = i0 + 1;
                float w0 = (i0 >= 0 && i0 < T_) ? (1.f - frac) : 0.f;
                float w1 = (i1 >= 0 && i1 < T_) ? frac : 0.f;
                int i0c = min(max(i0, 0), T_ - 1);
                int i1c = min(max(i1, 0), T_ - 1);
                const float* xc = x + ((size_t)n * CIN + gci) * (T_ * V_);
                float xv = w0 * xc[i0c * V_ + v_in] + w1 * xc[i1c * V_ + v_in];
                hv = a1[gci] * xv + b1[gci] * (w0 + w1);
            }
            sh[ci][lt][vv] = hv;
        }
        __syncthreads();

#pragma unroll 1
        for (int ci = 0; ci < CI_CHUNK; ci++) {
            float xv[3][3];
#pragma unroll
            for (int kt = 0; kt < 3; kt++) {
                const float2* rp = reinterpret_cast<const float2*>(&sh[ci][2 * tq + kt][2 * voc]);
                float2 p0 = rp[0];
                float2 p1 = rp[1];
                xv[kt][0] = p0.x; xv[kt][1] = p0.y; xv[kt][2] = p1.x;
            }
            const float* wrow = w32 + ((size_t)(cc + ci) * COUT + co_w) * 9;
#pragma unroll
            for (int j = 0; j < 16; j++) {
                const float* wj = wrow + j * 9;
                float a = acc[j];
                a += wj[0] * xv[0][0];
                a += wj[1] * xv[0][1];
                a += wj[2] * xv[0][2];
                a += wj[3] * xv[1][0];
                a += wj[4] * xv[1][1];
                a += wj[5] * xv[1][2];
                a += wj[6] * xv[2][0];
                a += wj[7] * xv[2][1];
                a += wj[8] * xv[2][2];
                acc[j] = a;
            }
        }
        __syncthreads();
    }

    if (vo < VOUT) {
#pragma unroll
        for (int j = 0; j < 16; j++) {
            int co = co_w + j;
            float bi = bias[co];
            float* yp = y + (((size_t)n * COUT + co) * TOUT + to) * VOUT;
            yp[vo] = fmaxf(acc[j] + bi, 0.f);
        }
    }
}

// ---- BN2 stats over z = shift_out(y): one block per output channel ----
template<int MODE, typename DT>
__global__ void bn2_k(const int* __restrict__ flag, const DT* __restrict__ y,
                      const DT* __restrict__ s_out,
                      const DT* __restrict__ gamma, const DT* __restrict__ beta,
                      float* __restrict__ a2, float* __restrict__ b2) {
    if (flag[0] != MODE) return;
    int co = blockIdx.x;
    float sv = ldv(&s_out[co]);
    float s = 0.f, ss = 0.f;
    for (int i = threadIdx.x; i < N_ * TOUT * VOUT; i += 256) {
        int n = i / (TOUT * VOUT);
        int r = i % (TOUT * VOUT);
        int to = r / VOUT;
        int vo = r % VOUT;
        float tsrc = (float)to + sv;
        float f0 = floorf(tsrc);
        float frac = tsrc - f0;
        int i0 = (int)f0, i1 = i0 + 1;
        float w0 = (i0 >= 0 && i0 < TOUT) ? (1.f - frac) : 0.f;
        float w1 = (i1 >= 0 && i1 < TOUT) ? frac : 0.f;
        int i0c = min(max(i0, 0), TOUT - 1);
        int i1c = min(max(i1, 0), TOUT - 1);
        const DT* yc = y + ((size_t)n * COUT + co) * (TOUT * VOUT);
        float z = w0 * ldv(&yc[i0c * VOUT + vo]) + w1 * ldv(&yc[i1c * VOUT + vo]);
        s += z; ss += z * z;
    }
    blockReduce2(s, ss);
    if (threadIdx.x == 0) {
        float cnt = (float)(N_ * TOUT * VOUT);
        float mean = s / cnt;
        float var = ss / cnt - mean * mean;
        float a = ldv(&gamma[co]) * rsqrtf(var + EPS_);
        a2[co] = a;
        b2[co] = ldv(&beta[co]) - mean * a;
    }
}

// ---- in-place: out = a2 * shift_out(y) + b2, per (n,co) plane via LDS ----
template<int MODE, typename DT>
__global__ void final_k(const int* __restrict__ flag, DT* __restrict__ y,
                        const DT* __restrict__ s_out,
                        const float* __restrict__ a2, const float* __restrict__ b2) {
    if (flag[0] != MODE) return;
    __shared__ float pl[TOUT * VOUT];
    int co = blockIdx.x, n = blockIdx.y;
    DT* base = y + ((size_t)n * COUT + co) * (TOUT * VOUT);
    for (int i = threadIdx.x; i < TOUT * VOUT; i += 256) pl[i] = ldv(&base[i]);
    __syncthreads();
    float sv = ldv(&s_out[co]);
    float A = a2[co], B = b2[co];
    for (int i = threadIdx.x; i < TOUT * VOUT; i += 256) {
        int to = i / VOUT, vo = i % VOUT;
        float tsrc = (float)to + sv;
        float f0 = floorf(tsrc);
        float frac = tsrc - f0;
        int i0 = (int)f0, i1 = i0 + 1;
        float w0 = (i0 >= 0 && i0 < TOUT) ? (1.f - frac) : 0.f;
        float w1 = (i1 >= 0 && i1 < TOUT) ? frac : 0.f;
        int i0c = min(max(i0, 0), TOUT - 1);
        int i1c = min(max(i1, 0), TOUT - 1);
        float z = w0 * pl[i0c * VOUT + vo] + w1 * pl[i1c * VOUT + vo];
        stv(&base[i], A * z + B);
    }
}

extern "C" void kernel_launch(void* const* d_in, const int* in_sizes, int n_in,
                              void* d_out, int out_size, void* d_ws, size_t ws_size,
                              hipStream_t stream) {
    // ws: flag (256B) | a1[128] | b1[128] | a2[256] | b2[256] | s1[128] | q1[128]
    //     | @8192: weight buffer (1.18 MB) shared by the two modes (only one runs):
    //       MODE1: w32 fp32 [ci][co][9];  MODE0: w2u packed bf16-dup [tap][co][k]
    int*   flag = (int*)d_ws;
    float* a1 = (float*)((char*)d_ws + 256);
    float* b1 = a1 + 128;
    float* a2 = b1 + 128;
    float* b2 = a2 + 256;
    float* s1 = b2 + 256;
    float* q1 = s1 + 128;
    float*    w32 = (float*)((char*)d_ws + 8192);
    unsigned* w2u = (unsigned*)((char*)d_ws + 8192);

    detect_k<<<1, 256, 0, stream>>>((const unsigned short*)d_in[0], flag, s1, q1);

    // MODE 0: bf16 tensors
    const bf16* xb    = (const bf16*)d_in[0];
    const bf16* g1b   = (const bf16*)d_in[1];
    const bf16* be1b  = (const bf16*)d_in[2];
    const bf16* sinb  = (const bf16*)d_in[3];
    const bf16* cbb   = (const bf16*)d_in[5];
    const bf16* soutb = (const bf16*)d_in[6];
    const bf16* g2b   = (const bf16*)d_in[7];
    const bf16* be2b  = (const bf16*)d_in[8];
    bf16* yb = (bf16*)d_out;
    // MODE 1: fp32 tensors
    const float* xf    = (const float*)d_in[0];
    const float* g1f   = (const float*)d_in[1];
    const float* be1f  = (const float*)d_in[2];
    const float* sinf_ = (const float*)d_in[3];
    const float* wbf   = (const float*)d_in[4];
    const float* cbf   = (const float*)d_in[5];
    const float* soutf = (const float*)d_in[6];
    const float* g2f   = (const float*)d_in[7];
    const float* be2f  = (const float*)d_in[8];
    float* yf = (float*)d_out;

    wcvt2_k<<<dim3(64), 256, 0, stream>>>(flag, (const unsigned short*)d_in[4], w2u);
    wcvt_k <<<dim3(64), 256, 0, stream>>>(flag, wbf, w32);

    bn1_k<0, bf16> <<<dim3(CIN, 4), 256, 0, stream>>>(flag, xb, s1, q1);
    bn1_k<1, float><<<dim3(CIN, 4), 256, 0, stream>>>(flag, xf, s1, q1);
    bn1fin_k<0, bf16> <<<1, 128, 0, stream>>>(flag, g1b, be1b, s1, q1, a1, b1);
    bn1fin_k<1, float><<<1, 128, 0, stream>>>(flag, g1f, be1f, s1, q1, a1, b1);

    conv_mfma_k<<<dim3(TOUT / 4, N_), 256, 0, stream>>>(flag, xb, w2u, cbb, sinb, a1, b1, yb);
    conv_f32_k <<<dim3(TOUT / 4, COUT / 64, N_), 256, 0, stream>>>(flag, xf, w32, cbf, sinf_, a1, b1, yf);

    bn2_k<0, bf16> <<<dim3(COUT), 256, 0, stream>>>(flag, yb, soutb, g2b, be2b, a2, b2);
    bn2_k<1, float><<<dim3(COUT), 256, 0, stream>>>(flag, yf, soutf, g2f, be2f, a2, b2);

    final_k<0, bf16> <<<dim3(COUT, N_), 256, 0, stream>>>(flag, yb, soutb, a2, b2);
    final_k<1, float><<<dim3(COUT, N_), 256, 0, stream>>>(flag, yf, soutf, a2, b2);
}

// Round 6
// 692.820 us; speedup vs baseline: 1.5353x; 1.5353x over previous
//
#include <hip/hip_runtime.h>
#include <hip/hip_bf16.h>

#define N_    64
#define CIN   128
#define COUT  256
#define T_    128
#define V_    25
#define TOUT  64
#define VOUT  13
#define EPS_  1e-5f

typedef __hip_bfloat16 bf16;
typedef __attribute__((ext_vector_type(8))) short short8x;
typedef __attribute__((ext_vector_type(4))) float f32x4;

__device__ __forceinline__ float ldv(const bf16* p)  { return __bfloat162float(*p); }
__device__ __forceinline__ float ldv(const float* p) { return *p; }
__device__ __forceinline__ void  stv(bf16* p, float v)  { *p = __float2bfloat16(v); }
__device__ __forceinline__ void  stv(float* p, float v) { *p = v; }

__device__ __forceinline__ unsigned bf16rne(float f) {
    unsigned u = __float_as_uint(f);
    return (u + 0x7FFFu + ((u >> 16) & 1u)) >> 16;
}

// vectorized 4-element load -> 4 floats
__device__ __forceinline__ void load4(const float* p, float& a, float& b, float& c, float& d) {
    float4 v = *reinterpret_cast<const float4*>(p);
    a = v.x; b = v.y; c = v.z; d = v.w;
}
__device__ __forceinline__ void load4(const bf16* p, float& a, float& b, float& c, float& d) {
    ushort4 u = *reinterpret_cast<const ushort4*>(p);
    a = __uint_as_float((unsigned)u.x << 16);
    b = __uint_as_float((unsigned)u.y << 16);
    c = __uint_as_float((unsigned)u.z << 16);
    d = __uint_as_float((unsigned)u.w << 16);
}

// Reduce (s, ss) across a 256-thread block; valid in thread 0 afterwards.
__device__ __forceinline__ void blockReduce2(float& s, float& ss) {
    __shared__ float ls[4], lss[4];
    int lane = threadIdx.x & 63, wid = threadIdx.x >> 6;
#pragma unroll
    for (int o = 32; o > 0; o >>= 1) {
        s  += __shfl_down(s, o, 64);
        ss += __shfl_down(ss, o, 64);
    }
    if (lane == 0) { ls[wid] = s; lss[wid] = ss; }
    __syncthreads();
    if (threadIdx.x == 0) {
        s  = ls[0] + ls[1] + ls[2] + ls[3];
        ss = lss[0] + lss[1] + lss[2] + lss[3];
    }
}

// ---- dtype detector + zero-init of bn1/bn2 partial sums (graph-replay reset) ----
__global__ void detect_k(const unsigned short* __restrict__ xr, int* flag,
                         float* __restrict__ s1, float* __restrict__ q1,
                         float* __restrict__ s2, float* __restrict__ q2) {
    if (threadIdx.x < CIN) { s1[threadIdx.x] = 0.f; q1[threadIdx.x] = 0.f; }
    s2[threadIdx.x] = 0.f; q2[threadIdx.x] = 0.f;  // 256 threads cover COUT
    __shared__ int cnt;
    if (threadIdx.x == 0) cnt = 0;
    __syncthreads();
    int c = 0;
    for (int i = threadIdx.x; i < 8192; i += 256) {
        int e = (xr[i] >> 7) & 0xFF;
        if (e >= 192) c++;
    }
    atomicAdd(&cnt, c);
    __syncthreads();
    if (threadIdx.x == 0) flag[0] = (cnt > 0) ? 1 : 0;
}

// ---- weight prepass: split into bf16 hi/lo, duplicated pairs, layout [tap][co][ci] ----
// whi[(tap*COUT+co)*CIN+ci] = hi|hi<<16  (k=2ci,2ci+1)
// wlo[...]                  = lo|lo<<16
// For bf16 weights (MODE 0) lo = 0 automatically.
template<int MODE, typename DT>
__global__ __launch_bounds__(256) void wprep_k(const int* __restrict__ flag,
                                               const DT* __restrict__ wgt,
                                               unsigned* __restrict__ whi,
                                               unsigned* __restrict__ wlo) {
    if (flag[0] != MODE) return;
    int total = COUT * CIN * 9;
    for (int i = blockIdx.x * 256 + threadIdx.x; i < total; i += gridDim.x * 256) {
        int co = i / (CIN * 9);
        int r  = i - co * (CIN * 9);
        int ci = r / 9;
        int k9 = r - ci * 9;
        float w = ldv(&wgt[i]);
        unsigned hb = bf16rne(w);
        float hif = __uint_as_float(hb << 16);
        unsigned lb = bf16rne(w - hif);
        size_t idx = ((size_t)k9 * COUT + co) * CIN + ci;
        whi[idx] = hb | (hb << 16);
        wlo[idx] = lb | (lb << 16);
    }
}

// ---- BN1 partial sums: grid (CIN, 4), vectorized loads, atomic accumulate ----
template<int MODE, typename DT>
__global__ __launch_bounds__(256) void bn1_k(const int* __restrict__ flag,
                                             const DT* __restrict__ x,
                                             float* __restrict__ s1, float* __restrict__ q1) {
    if (flag[0] != MODE) return;
    const int c  = blockIdx.x;
    const int n0 = blockIdx.y * (N_ / 4);
    float s = 0.f, ss = 0.f;
    for (int idx = threadIdx.x; idx < (N_ / 4) * 800; idx += 256) {
        int n = n0 + idx / 800;
        int q = idx - (idx / 800) * 800;
        const DT* xp = x + ((size_t)n * CIN + c) * (T_ * V_) + q * 4;
        float v0, v1, v2, v3;
        load4(xp, v0, v1, v2, v3);
        s  += (v0 + v1) + (v2 + v3);
        ss += (v0 * v0 + v1 * v1) + (v2 * v2 + v3 * v3);
    }
    blockReduce2(s, ss);
    if (threadIdx.x == 0) { atomicAdd(&s1[c], s); atomicAdd(&q1[c], ss); }
}

// ---- BN1 finalize: a1,b1 from partial sums ----
template<int MODE, typename DT>
__global__ void bn1fin_k(const int* __restrict__ flag,
                         const DT* __restrict__ gamma, const DT* __restrict__ beta,
                         const float* __restrict__ s1, const float* __restrict__ q1,
                         float* __restrict__ a1, float* __restrict__ b1) {
    if (flag[0] != MODE) return;
    int c = threadIdx.x;  // 128 threads
    float cnt = (float)(N_ * T_ * V_);
    float mean = s1[c] / cnt;
    float var = q1[c] / cnt - mean * mean;
    float a = ldv(&gamma[c]) * rsqrtf(var + EPS_);
    a1[c] = a;
    b1[c] = ldv(&beta[c]) - mean * a;
}

// ================= fused shift_in + BN1 + conv (MFMA, split precision) =================
// Block: (tg = 4 'to', n), 256 thr = 4 waves. Wave w owns co [w*64, w*64+64)
// (4 M-tiles of 16) x 4 to (N = 16 vo slots, 13 valid).
// K per tap = 2*CIN: k=2ci -> hi slot, k=2ci+1 -> lo slot.
// H staged in LDS as u32 = h_hi | h_lo<<16 per ci; pass1 A=(w_hi,w_hi) gives
// w_hi*(h_hi+h_lo); pass2 A=(w_lo,w_lo) gives w_lo*(h_hi+h_lo). Sum = w*h
// up to split error ~2^-17 (fp32-grade).
// LDS: [lt 9][vv 27][ci 36pad] u32 = 35 KB.
template<int MODE, typename DT>
__global__ __launch_bounds__(256) void conv_mfma_k(const int* __restrict__ flag,
                                                   const DT* __restrict__ x,
                                                   const unsigned* __restrict__ whi,
                                                   const unsigned* __restrict__ wlo,
                                                   const DT* __restrict__ bias,
                                                   const DT* __restrict__ s_in,
                                                   const float* __restrict__ a1,
                                                   const float* __restrict__ b1,
                                                   DT* __restrict__ y) {
    if (flag[0] != MODE) return;
    __shared__ __align__(16) unsigned shp[9 * 27 * 36];
    const int tg    = blockIdx.x;       // 0..15
    const int n     = blockIdx.y;       // 0..63
    const int tid   = threadIdx.x;
    const int wv    = tid >> 6;         // wave id -> co block
    const int lane  = tid & 63;
    const int khi   = lane >> 4;        // 0..3 : k-group
    const int ln16  = lane & 15;        // m (co) for A; n (vo) for B/C
    const int wbase = wv * 64;
    const int tbase = 8 * tg - 1;       // t_in = tbase + lt, lt in [0,9)

    const short8x* shv = reinterpret_cast<const short8x*>(shp);

    f32x4 acc[4][4];
#pragma unroll
    for (int ct = 0; ct < 4; ct++)
#pragma unroll
        for (int tt = 0; tt < 4; tt++) acc[ct][tt] = (f32x4){0.f, 0.f, 0.f, 0.f};

#pragma unroll 1
    for (int cc = 0; cc < 4; cc++) {    // ci chunks of 32
        __syncthreads();
        // ---- stage shift_in + BN1 chunk, bf16 hi/lo packed ----
        for (int e = tid; e < 32 * 9 * 27; e += 256) {
            int vv = e % 27;
            int r0 = e / 27;
            int lt = r0 % 9;
            int ci = r0 / 9;
            int gci  = cc * 32 + ci;
            int t_in = tbase + lt;
            int v_in = vv - 1;
            float hv = 0.f;
            if (t_in >= 0 && t_in < T_ && v_in >= 0 && v_in < V_) {
                float s = ldv(&s_in[gci]);
                float tsrc = (float)t_in + s;
                float f0 = floorf(tsrc);
                float frac = tsrc - f0;
                int i0 = (int)f0;
                int i1 = i0 + 1;
                float w0 = (i0 >= 0 && i0 < T_) ? (1.f - frac) : 0.f;
                float w1 = (i1 >= 0 && i1 < T_) ? frac : 0.f;
                int i0c = min(max(i0, 0), T_ - 1);
                int i1c = min(max(i1, 0), T_ - 1);
                const DT* xc = x + ((size_t)n * CIN + gci) * (T_ * V_);
                float xv = w0 * ldv(&xc[i0c * V_ + v_in]) + w1 * ldv(&xc[i1c * V_ + v_in]);
                hv = a1[gci] * xv + b1[gci] * (w0 + w1);
            }
            unsigned hb = bf16rne(hv);
            float hif = __uint_as_float(hb << 16);
            unsigned lb = bf16rne(hv - hif);
            shp[(lt * 27 + vv) * 36 + ci] = hb | (lb << 16);
        }
        __syncthreads();

        // ---- MFMA over 9 taps, 2 precision passes sharing B ----
#pragma unroll 1
        for (int kt = 0; kt < 3; kt++) {
#pragma unroll 1
            for (int kv = 0; kv < 3; kv++) {
                const int tap = kt * 3 + kv;
                const int vvc = min(2 * ln16 + kv, 26);
                const int cobase0 = (tap * COUT + wbase + ln16) * 32 + cc * 8 + khi;
#pragma unroll
                for (int pass = 0; pass < 2; pass++) {
                    const short8x* wv8 = reinterpret_cast<const short8x*>(pass ? wlo : whi);
                    // A fragments: 4 co-tiles x 2 k-steps (16B, wave-gather, L2-hot)
                    short8x af[4][2];
#pragma unroll
                    for (int ct = 0; ct < 4; ct++) {
#pragma unroll
                        for (int ks = 0; ks < 2; ks++)
                            af[ct][ks] = wv8[cobase0 + ct * 16 * 32 + ks * 4];
                    }
#pragma unroll
                    for (int tt = 0; tt < 4; tt++) {
                        const int lt = 2 * tt + kt;
                        const int rb = (lt * 27 + vvc) * 9 + khi;
                        short8x b0 = shv[rb];
                        short8x b1 = shv[rb + 4];
#pragma unroll
                        for (int ct = 0; ct < 4; ct++) {
                            acc[ct][tt] = __builtin_amdgcn_mfma_f32_16x16x32_bf16(af[ct][0], b0, acc[ct][tt], 0, 0, 0);
                            acc[ct][tt] = __builtin_amdgcn_mfma_f32_16x16x32_bf16(af[ct][1], b1, acc[ct][tt], 0, 0, 0);
                        }
                    }
                }
            }
        }
    }

    // ---- epilogue: bias + relu + store (C: col=lane&15 -> vo, row=khi*4+r -> co) ----
    if (ln16 < VOUT) {
#pragma unroll
        for (int ct = 0; ct < 4; ct++) {
#pragma unroll
            for (int r = 0; r < 4; r++) {
                const int co = wbase + ct * 16 + khi * 4 + r;
                const float bi = ldv(&bias[co]);
#pragma unroll
                for (int tt = 0; tt < 4; tt++) {
                    const int to = tg * 4 + tt;
                    DT* yp = y + (((size_t)n * COUT + co) * TOUT + to) * VOUT;
                    stv(&yp[ln16], fmaxf(acc[ct][tt][r] + bi, 0.f));
                }
            }
        }
    }
}

// ---- BN2 partial sums over z = shift_out(y): grid (COUT, 4), atomic accumulate ----
template<int MODE, typename DT>
__global__ __launch_bounds__(256) void bn2_k(const int* __restrict__ flag, const DT* __restrict__ y,
                                             const DT* __restrict__ s_out,
                                             float* __restrict__ s2, float* __restrict__ q2) {
    if (flag[0] != MODE) return;
    int co = blockIdx.x;
    int n0 = blockIdx.y * (N_ / 4);
    float sv = ldv(&s_out[co]);
    float s = 0.f, ss = 0.f;
    for (int i = threadIdx.x; i < (N_ / 4) * TOUT * VOUT; i += 256) {
        int n = n0 + i / (TOUT * VOUT);
        int r = i % (TOUT * VOUT);
        int to = r / VOUT;
        int vo = r % VOUT;
        float tsrc = (float)to + sv;
        float f0 = floorf(tsrc);
        float frac = tsrc - f0;
        int i0 = (int)f0, i1 = i0 + 1;
        float w0 = (i0 >= 0 && i0 < TOUT) ? (1.f - frac) : 0.f;
        float w1 = (i1 >= 0 && i1 < TOUT) ? frac : 0.f;
        int i0c = min(max(i0, 0), TOUT - 1);
        int i1c = min(max(i1, 0), TOUT - 1);
        const DT* yc = y + ((size_t)n * COUT + co) * (TOUT * VOUT);
        float z = w0 * ldv(&yc[i0c * VOUT + vo]) + w1 * ldv(&yc[i1c * VOUT + vo]);
        s += z; ss += z * z;
    }
    blockReduce2(s, ss);
    if (threadIdx.x == 0) { atomicAdd(&s2[co], s); atomicAdd(&q2[co], ss); }
}

// ---- BN2 finalize ----
template<int MODE, typename DT>
__global__ void bn2fin_k(const int* __restrict__ flag,
                         const DT* __restrict__ gamma, const DT* __restrict__ beta,
                         const float* __restrict__ s2, const float* __restrict__ q2,
                         float* __restrict__ a2, float* __restrict__ b2) {
    if (flag[0] != MODE) return;
    int c = threadIdx.x;  // 256 threads
    float cnt = (float)(N_ * TOUT * VOUT);
    float mean = s2[c] / cnt;
    float var = q2[c] / cnt - mean * mean;
    float a = ldv(&gamma[c]) * rsqrtf(var + EPS_);
    a2[c] = a;
    b2[c] = ldv(&beta[c]) - mean * a;
}

// ---- in-place: out = a2 * shift_out(y) + b2, per (n,co) plane via LDS ----
template<int MODE, typename DT>
__global__ void final_k(const int* __restrict__ flag, DT* __restrict__ y,
                        const DT* __restrict__ s_out,
                        const float* __restrict__ a2, const float* __restrict__ b2) {
    if (flag[0] != MODE) return;
    __shared__ float pl[TOUT * VOUT];
    int co = blockIdx.x, n = blockIdx.y;
    DT* base = y + ((size_t)n * COUT + co) * (TOUT * VOUT);
    for (int i = threadIdx.x; i < TOUT * VOUT; i += 256) pl[i] = ldv(&base[i]);
    __syncthreads();
    float sv = ldv(&s_out[co]);
    float A = a2[co], B = b2[co];
    for (int i = threadIdx.x; i < TOUT * VOUT; i += 256) {
        int to = i / VOUT, vo = i % VOUT;
        float tsrc = (float)to + sv;
        float f0 = floorf(tsrc);
        float frac = tsrc - f0;
        int i0 = (int)f0, i1 = i0 + 1;
        float w0 = (i0 >= 0 && i0 < TOUT) ? (1.f - frac) : 0.f;
        float w1 = (i1 >= 0 && i1 < TOUT) ? frac : 0.f;
        int i0c = min(max(i0, 0), TOUT - 1);
        int i1c = min(max(i1, 0), TOUT - 1);
        float z = w0 * pl[i0c * VOUT + vo] + w1 * pl[i1c * VOUT + vo];
        stv(&base[i], A * z + B);
    }
}

extern "C" void kernel_launch(void* const* d_in, const int* in_sizes, int n_in,
                              void* d_out, int out_size, void* d_ws, size_t ws_size,
                              hipStream_t stream) {
    // ws: flag(256B) | a1[128] b1[128] a2[256] b2[256] s1[128] q1[128] s2[256] q2[256]
    //     | @8192: whi (1.18 MB) | wlo (1.18 MB)   -- bf16 hi/lo split weights
    int*   flag = (int*)d_ws;
    float* a1 = (float*)((char*)d_ws + 256);
    float* b1 = a1 + 128;
    float* a2 = b1 + 128;
    float* b2 = a2 + 256;
    float* s1 = b2 + 256;
    float* q1 = s1 + 128;
    float* s2 = q1 + 128;
    float* q2 = s2 + 256;
    unsigned* whi = (unsigned*)((char*)d_ws + 8192);
    unsigned* wlo = whi + (size_t)9 * COUT * CIN;

    detect_k<<<1, 256, 0, stream>>>((const unsigned short*)d_in[0], flag, s1, q1, s2, q2);

    // MODE 0: bf16 tensors
    const bf16* xb    = (const bf16*)d_in[0];
    const bf16* g1b   = (const bf16*)d_in[1];
    const bf16* be1b  = (const bf16*)d_in[2];
    const bf16* sinb  = (const bf16*)d_in[3];
    const bf16* wbb   = (const bf16*)d_in[4];
    const bf16* cbb   = (const bf16*)d_in[5];
    const bf16* soutb = (const bf16*)d_in[6];
    const bf16* g2b   = (const bf16*)d_in[7];
    const bf16* be2b  = (const bf16*)d_in[8];
    bf16* yb = (bf16*)d_out;
    // MODE 1: fp32 tensors
    const float* xf    = (const float*)d_in[0];
    const float* g1f   = (const float*)d_in[1];
    const float* be1f  = (const float*)d_in[2];
    const float* sinf_ = (const float*)d_in[3];
    const float* wbf   = (const float*)d_in[4];
    const float* cbf   = (const float*)d_in[5];
    const float* soutf = (const float*)d_in[6];
    const float* g2f   = (const float*)d_in[7];
    const float* be2f  = (const float*)d_in[8];
    float* yf = (float*)d_out;

    wprep_k<0, bf16> <<<dim3(64), 256, 0, stream>>>(flag, wbb, whi, wlo);
    wprep_k<1, float><<<dim3(64), 256, 0, stream>>>(flag, wbf, whi, wlo);

    bn1_k<0, bf16> <<<dim3(CIN, 4), 256, 0, stream>>>(flag, xb, s1, q1);
    bn1_k<1, float><<<dim3(CIN, 4), 256, 0, stream>>>(flag, xf, s1, q1);
    bn1fin_k<0, bf16> <<<1, 128, 0, stream>>>(flag, g1b, be1b, s1, q1, a1, b1);
    bn1fin_k<1, float><<<1, 128, 0, stream>>>(flag, g1f, be1f, s1, q1, a1, b1);

    conv_mfma_k<0, bf16> <<<dim3(TOUT / 4, N_), 256, 0, stream>>>(flag, xb, whi, wlo, cbb, sinb, a1, b1, yb);
    conv_mfma_k<1, float><<<dim3(TOUT / 4, N_), 256, 0, stream>>>(flag, xf, whi, wlo, cbf, sinf_, a1, b1, yf);

    bn2_k<0, bf16> <<<dim3(COUT, 4), 256, 0, stream>>>(flag, yb, soutb, s2, q2);
    bn2_k<1, float><<<dim3(COUT, 4), 256, 0, stream>>>(flag, yf, soutf, s2, q2);
    bn2fin_k<0, bf16> <<<1, 256, 0, stream>>>(flag, g2b, be2b, s2, q2, a2, b2);
    bn2fin_k<1, float><<<1, 256, 0, stream>>>(flag, g2f, be2f, s2, q2, a2, b2);

    final_k<0, bf16> <<<dim3(COUT, N_), 256, 0, stream>>>(flag, yb, soutb, a2, b2);
    final_k<1, float><<<dim3(COUT, N_), 256, 0, stream>>>(flag, yf, soutf, a2, b2);
}

// Round 7
// 528.084 us; speedup vs baseline: 2.0143x; 1.3120x over previous
//
#include <hip/hip_runtime.h>
#include <hip/hip_bf16.h>

#define N_    64
#define CIN   128
#define COUT  256
#define T_    128
#define V_    25
#define TOUT  64
#define VOUT  13
#define EPS_  1e-5f

typedef __hip_bfloat16 bf16;
typedef __attribute__((ext_vector_type(8))) short short8x;
typedef __attribute__((ext_vector_type(4))) float f32x4;

__device__ __forceinline__ float ldv(const bf16* p)  { return __bfloat162float(*p); }
__device__ __forceinline__ float ldv(const float* p) { return *p; }
__device__ __forceinline__ void  stv(bf16* p, float v)  { *p = __float2bfloat16(v); }
__device__ __forceinline__ void  stv(float* p, float v) { *p = v; }

__device__ __forceinline__ unsigned bf16rne(float f) {
    unsigned u = __float_as_uint(f);
    return (u + 0x7FFFu + ((u >> 16) & 1u)) >> 16;
}

// non-temporal loads (streaming: keep weights L2-resident)
__device__ __forceinline__ float ldnt(const float* p) { return __builtin_nontemporal_load(p); }
__device__ __forceinline__ float ldnt(const bf16* p) {
    unsigned short u = __builtin_nontemporal_load((const unsigned short*)p);
    return __uint_as_float((unsigned)u << 16);
}
__device__ __forceinline__ void stnt(float* p, float v) { __builtin_nontemporal_store(v, p); }
__device__ __forceinline__ void stnt(bf16* p, float v) {
    unsigned short u = (unsigned short)bf16rne(v);
    __builtin_nontemporal_store(u, (unsigned short*)p);
}

// vectorized 4-element load -> 4 floats
__device__ __forceinline__ void load4(const float* p, float& a, float& b, float& c, float& d) {
    float4 v = *reinterpret_cast<const float4*>(p);
    a = v.x; b = v.y; c = v.z; d = v.w;
}
__device__ __forceinline__ void load4(const bf16* p, float& a, float& b, float& c, float& d) {
    ushort4 u = *reinterpret_cast<const ushort4*>(p);
    a = __uint_as_float((unsigned)u.x << 16);
    b = __uint_as_float((unsigned)u.y << 16);
    c = __uint_as_float((unsigned)u.z << 16);
    d = __uint_as_float((unsigned)u.w << 16);
}

// Reduce (s, ss) across a 256-thread block; valid in thread 0 afterwards.
__device__ __forceinline__ void blockReduce2(float& s, float& ss) {
    __shared__ float ls[4], lss[4];
    int lane = threadIdx.x & 63, wid = threadIdx.x >> 6;
#pragma unroll
    for (int o = 32; o > 0; o >>= 1) {
        s  += __shfl_down(s, o, 64);
        ss += __shfl_down(ss, o, 64);
    }
    if (lane == 0) { ls[wid] = s; lss[wid] = ss; }
    __syncthreads();
    if (threadIdx.x == 0) {
        s  = ls[0] + ls[1] + ls[2] + ls[3];
        ss = lss[0] + lss[1] + lss[2] + lss[3];
    }
}

// ---- dtype detector + zero-init of bn1/bn2 partial sums (graph-replay reset) ----
__global__ void detect_k(const unsigned short* __restrict__ xr, int* flag,
                         float* __restrict__ s1, float* __restrict__ q1,
                         float* __restrict__ s2, float* __restrict__ q2) {
    if (threadIdx.x < CIN) { s1[threadIdx.x] = 0.f; q1[threadIdx.x] = 0.f; }
    s2[threadIdx.x] = 0.f; q2[threadIdx.x] = 0.f;  // 256 threads cover COUT
    __shared__ int cnt;
    if (threadIdx.x == 0) cnt = 0;
    __syncthreads();
    int c = 0;
    for (int i = threadIdx.x; i < 8192; i += 256) {
        int e = (xr[i] >> 7) & 0xFF;
        if (e >= 192) c++;
    }
    atomicAdd(&cnt, c);
    __syncthreads();
    if (threadIdx.x == 0) flag[0] = (cnt > 0) ? 1 : 0;
}

// ---- weight prepass: bf16 hi/lo split in EXACT MFMA-fragment order ----
// fragment f = ((tap*2+pass)*16 + ctg)*8 + ch   (ctg = co/16, ch = ci/16)
// u32 o = f*256 + lane*4 + j holds dup(hi or lo of w[co][ci][tap])
//   with co = ctg*16 + (lane&15), ci = ch*16 + (lane>>4)*4 + j.
// => in conv, each A-fragment is ONE fully-coalesced 1KB load at base+lane*16.
template<int MODE, typename DT>
__global__ __launch_bounds__(256) void wprep_k(const int* __restrict__ flag,
                                               const DT* __restrict__ wgt,
                                               unsigned* __restrict__ wfrag) {
    if (flag[0] != MODE) return;
    const int total = 2304 * 256;
    for (int o = blockIdx.x * 256 + threadIdx.x; o < total; o += gridDim.x * 256) {
        int j    = o & 3;
        int lane = (o >> 2) & 63;
        int f    = o >> 8;
        int ch   = f & 7;
        int ctg  = (f >> 3) & 15;
        int pp   = f >> 7;        // 0..17
        int pass = pp & 1;
        int tap  = pp >> 1;
        int co = ctg * 16 + (lane & 15);
        int ci = ch * 16 + (lane >> 4) * 4 + j;
        float w = ldv(&wgt[((size_t)co * CIN + ci) * 9 + tap]);
        unsigned hb = bf16rne(w);
        unsigned val;
        if (pass == 0) {
            val = hb | (hb << 16);
        } else {
            float hif = __uint_as_float(hb << 16);
            unsigned lb = bf16rne(w - hif);
            val = lb | (lb << 16);
        }
        wfrag[o] = val;
    }
}

// ---- BN1 partial sums: grid (CIN, 4), vectorized loads, atomic accumulate ----
template<int MODE, typename DT>
__global__ __launch_bounds__(256) void bn1_k(const int* __restrict__ flag,
                                             const DT* __restrict__ x,
                                             float* __restrict__ s1, float* __restrict__ q1) {
    if (flag[0] != MODE) return;
    const int c  = blockIdx.x;
    const int n0 = blockIdx.y * (N_ / 4);
    float s = 0.f, ss = 0.f;
    for (int idx = threadIdx.x; idx < (N_ / 4) * 800; idx += 256) {
        int n = n0 + idx / 800;
        int q = idx - (idx / 800) * 800;
        const DT* xp = x + ((size_t)n * CIN + c) * (T_ * V_) + q * 4;
        float v0, v1, v2, v3;
        load4(xp, v0, v1, v2, v3);
        s  += (v0 + v1) + (v2 + v3);
        ss += (v0 * v0 + v1 * v1) + (v2 * v2 + v3 * v3);
    }
    blockReduce2(s, ss);
    if (threadIdx.x == 0) { atomicAdd(&s1[c], s); atomicAdd(&q1[c], ss); }
}

// ---- BN1 finalize: a1,b1 from partial sums ----
template<int MODE, typename DT>
__global__ void bn1fin_k(const int* __restrict__ flag,
                         const DT* __restrict__ gamma, const DT* __restrict__ beta,
                         const float* __restrict__ s1, const float* __restrict__ q1,
                         float* __restrict__ a1, float* __restrict__ b1) {
    if (flag[0] != MODE) return;
    int c = threadIdx.x;  // 128 threads
    float cnt = (float)(N_ * T_ * V_);
    float mean = s1[c] / cnt;
    float var = q1[c] / cnt - mean * mean;
    float a = ldv(&gamma[c]) * rsqrtf(var + EPS_);
    a1[c] = a;
    b1[c] = ldv(&beta[c]) - mean * a;
}

// ================= fused shift_in + BN1 + conv (MFMA, split precision) =================
// Block (tg = 4 'to', n), 4 waves; wave owns co [wv*64, wv*64+64).
// 16-ci chunks (8 of them); LDS single buffer [lt 9][vv 27][ci 20pad] u32 = 19.4 KB.
// Per chunk per wave: 9 taps x { 8 coalesced 1KB A-frag loads (both passes),
// 4 ds_read_b128 B-frags (shared across passes), 32 MFMA }.
#define CHUNK 16
#define CIPAD 20
template<int MODE, typename DT>
__global__ __launch_bounds__(256, 4) void conv_mfma_k(const int* __restrict__ flag,
                                                      const DT* __restrict__ x,
                                                      const unsigned* __restrict__ wfrag,
                                                      const DT* __restrict__ bias,
                                                      const DT* __restrict__ s_in,
                                                      const float* __restrict__ a1,
                                                      const float* __restrict__ b1,
                                                      DT* __restrict__ y) {
    if (flag[0] != MODE) return;
    __shared__ __align__(16) unsigned shp[9 * 27 * CIPAD];
    const int tg    = blockIdx.x;       // 0..15
    const int n     = blockIdx.y;       // 0..63
    const int tid   = threadIdx.x;
    const int wv    = tid >> 6;         // wave id -> co block (64 co)
    const int lane  = tid & 63;
    const int khi   = lane >> 4;        // 0..3 : k-group
    const int ln16  = lane & 15;        // m (co) for A; n (vo) for B/C
    const int tbase = 8 * tg - 1;       // t_in = tbase + lt, lt in [0,9)

    const short8x* wfl = reinterpret_cast<const short8x*>(wfrag) + lane;
    const short8x* shv = reinterpret_cast<const short8x*>(shp);

    f32x4 acc[4][4];
#pragma unroll
    for (int ct = 0; ct < 4; ct++)
#pragma unroll
        for (int tt = 0; tt < 4; tt++) acc[ct][tt] = (f32x4){0.f, 0.f, 0.f, 0.f};

#pragma unroll 1
    for (int ch = 0; ch < 8; ch++) {    // ci chunks of 16
        __syncthreads();                // prev chunk's reads done before overwrite
        // ---- stage shift_in + BN1 chunk, bf16 hi/lo packed (nt loads) ----
#pragma unroll 4
        for (int it = 0; it < 16; it++) {
            int e = it * 256 + tid;
            if (e < CHUNK * 9 * 27) {
                int vv = e % 27;
                int r0 = e / 27;
                int lt = r0 % 9;
                int ci = r0 / 9;
                int gci  = ch * 16 + ci;
                int t_in = tbase + lt;
                int v_in = vv - 1;
                float hv = 0.f;
                if (t_in >= 0 && t_in < T_ && v_in >= 0 && v_in < V_) {
                    float s = ldv(&s_in[gci]);
                    float tsrc = (float)t_in + s;
                    float f0 = floorf(tsrc);
                    float frac = tsrc - f0;
                    int i0 = (int)f0;
                    int i1 = i0 + 1;
                    float w0 = (i0 >= 0 && i0 < T_) ? (1.f - frac) : 0.f;
                    float w1 = (i1 >= 0 && i1 < T_) ? frac : 0.f;
                    int i0c = min(max(i0, 0), T_ - 1);
                    int i1c = min(max(i1, 0), T_ - 1);
                    const DT* xc = x + ((size_t)n * CIN + gci) * (T_ * V_);
                    float xv = w0 * ldnt(&xc[i0c * V_ + v_in]) + w1 * ldnt(&xc[i1c * V_ + v_in]);
                    hv = a1[gci] * xv + b1[gci] * (w0 + w1);
                }
                unsigned hb = bf16rne(hv);
                float hif = __uint_as_float(hb << 16);
                unsigned lb = bf16rne(hv - hif);
                shp[(lt * 27 + vv) * CIPAD + ci] = hb | (lb << 16);
            }
        }
        __syncthreads();

        // ---- MFMA: 9 taps; A both passes issued together; B shared across passes ----
#pragma unroll 1
        for (int kt = 0; kt < 3; kt++) {
#pragma unroll
            for (int kv = 0; kv < 3; kv++) {
                const int tap = kt * 3 + kv;
                const int vvc = min(2 * ln16 + kv, 26);
                // 8 coalesced A-fragment loads (2 passes x 4 co-tiles), all in flight
                short8x af[2][4];
#pragma unroll
                for (int pass = 0; pass < 2; pass++)
#pragma unroll
                    for (int ct = 0; ct < 4; ct++)
                        af[pass][ct] = wfl[(size_t)((((tap * 2 + pass) * 16 + wv * 4 + ct) * 8 + ch)) * 64];
#pragma unroll
                for (int tt = 0; tt < 4; tt++) {
                    const int lt = 2 * tt + kt;
                    short8x b = shv[(lt * 27 + vvc) * (CIPAD / 4) + khi];
#pragma unroll
                    for (int pass = 0; pass < 2; pass++)
#pragma unroll
                        for (int ct = 0; ct < 4; ct++)
                            acc[ct][tt] = __builtin_amdgcn_mfma_f32_16x16x32_bf16(af[pass][ct], b, acc[ct][tt], 0, 0, 0);
                }
            }
        }
    }

    // ---- epilogue: bias + relu + nt store (C: col=ln16 -> vo, row=khi*4+r -> co) ----
    if (ln16 < VOUT) {
#pragma unroll
        for (int ct = 0; ct < 4; ct++) {
#pragma unroll
            for (int r = 0; r < 4; r++) {
                const int co = wv * 64 + ct * 16 + khi * 4 + r;
                const float bi = ldv(&bias[co]);
#pragma unroll
                for (int tt = 0; tt < 4; tt++) {
                    const int to = tg * 4 + tt;
                    DT* yp = y + (((size_t)n * COUT + co) * TOUT + to) * VOUT;
                    stnt(&yp[ln16], fmaxf(acc[ct][tt][r] + bi, 0.f));
                }
            }
        }
    }
}

// ---- BN2 partial sums over z = shift_out(y): grid (COUT, 4), atomic accumulate ----
template<int MODE, typename DT>
__global__ __launch_bounds__(256) void bn2_k(const int* __restrict__ flag, const DT* __restrict__ y,
                                             const DT* __restrict__ s_out,
                                             float* __restrict__ s2, float* __restrict__ q2) {
    if (flag[0] != MODE) return;
    int co = blockIdx.x;
    int n0 = blockIdx.y * (N_ / 4);
    float sv = ldv(&s_out[co]);
    float s = 0.f, ss = 0.f;
    for (int i = threadIdx.x; i < (N_ / 4) * TOUT * VOUT; i += 256) {
        int n = n0 + i / (TOUT * VOUT);
        int r = i % (TOUT * VOUT);
        int to = r / VOUT;
        int vo = r % VOUT;
        float tsrc = (float)to + sv;
        float f0 = floorf(tsrc);
        float frac = tsrc - f0;
        int i0 = (int)f0, i1 = i0 + 1;
        float w0 = (i0 >= 0 && i0 < TOUT) ? (1.f - frac) : 0.f;
        float w1 = (i1 >= 0 && i1 < TOUT) ? frac : 0.f;
        int i0c = min(max(i0, 0), TOUT - 1);
        int i1c = min(max(i1, 0), TOUT - 1);
        const DT* yc = y + ((size_t)n * COUT + co) * (TOUT * VOUT);
        float z = w0 * ldv(&yc[i0c * VOUT + vo]) + w1 * ldv(&yc[i1c * VOUT + vo]);
        s += z; ss += z * z;
    }
    blockReduce2(s, ss);
    if (threadIdx.x == 0) { atomicAdd(&s2[co], s); atomicAdd(&q2[co], ss); }
}

// ---- BN2 finalize ----
template<int MODE, typename DT>
__global__ void bn2fin_k(const int* __restrict__ flag,
                         const DT* __restrict__ gamma, const DT* __restrict__ beta,
                         const float* __restrict__ s2, const float* __restrict__ q2,
                         float* __restrict__ a2, float* __restrict__ b2) {
    if (flag[0] != MODE) return;
    int c = threadIdx.x;  // 256 threads
    float cnt = (float)(N_ * TOUT * VOUT);
    float mean = s2[c] / cnt;
    float var = q2[c] / cnt - mean * mean;
    float a = ldv(&gamma[c]) * rsqrtf(var + EPS_);
    a2[c] = a;
    b2[c] = ldv(&beta[c]) - mean * a;
}

// ---- in-place: out = a2 * shift_out(y) + b2, per (n,co) plane via LDS ----
template<int MODE, typename DT>
__global__ void final_k(const int* __restrict__ flag, DT* __restrict__ y,
                        const DT* __restrict__ s_out,
                        const float* __restrict__ a2, const float* __restrict__ b2) {
    if (flag[0] != MODE) return;
    __shared__ float pl[TOUT * VOUT];
    int co = blockIdx.x, n = blockIdx.y;
    DT* base = y + ((size_t)n * COUT + co) * (TOUT * VOUT);
    for (int i = threadIdx.x; i < TOUT * VOUT; i += 256) pl[i] = ldv(&base[i]);
    __syncthreads();
    float sv = ldv(&s_out[co]);
    float A = a2[co], B = b2[co];
    for (int i = threadIdx.x; i < TOUT * VOUT; i += 256) {
        int to = i / VOUT, vo = i % VOUT;
        float tsrc = (float)to + sv;
        float f0 = floorf(tsrc);
        float frac = tsrc - f0;
        int i0 = (int)f0, i1 = i0 + 1;
        float w0 = (i0 >= 0 && i0 < TOUT) ? (1.f - frac) : 0.f;
        float w1 = (i1 >= 0 && i1 < TOUT) ? frac : 0.f;
        int i0c = min(max(i0, 0), TOUT - 1);
        int i1c = min(max(i1, 0), TOUT - 1);
        float z = w0 * pl[i0c * VOUT + vo] + w1 * pl[i1c * VOUT + vo];
        stv(&base[i], A * z + B);
    }
}

extern "C" void kernel_launch(void* const* d_in, const int* in_sizes, int n_in,
                              void* d_out, int out_size, void* d_ws, size_t ws_size,
                              hipStream_t stream) {
    // ws: flag(256B) | a1[128] b1[128] a2[256] b2[256] s1[128] q1[128] s2[256] q2[256]
    //     | @8192: wfrag (2.36 MB) -- fragment-ordered bf16 hi/lo split weights
    int*   flag = (int*)d_ws;
    float* a1 = (float*)((char*)d_ws + 256);
    float* b1 = a1 + 128;
    float* a2 = b1 + 128;
    float* b2 = a2 + 256;
    float* s1 = b2 + 256;
    float* q1 = s1 + 128;
    float* s2 = q1 + 128;
    float* q2 = s2 + 256;
    unsigned* wfrag = (unsigned*)((char*)d_ws + 8192);

    detect_k<<<1, 256, 0, stream>>>((const unsigned short*)d_in[0], flag, s1, q1, s2, q2);

    // MODE 0: bf16 tensors
    const bf16* xb    = (const bf16*)d_in[0];
    const bf16* g1b   = (const bf16*)d_in[1];
    const bf16* be1b  = (const bf16*)d_in[2];
    const bf16* sinb  = (const bf16*)d_in[3];
    const bf16* wbb   = (const bf16*)d_in[4];
    const bf16* cbb   = (const bf16*)d_in[5];
    const bf16* soutb = (const bf16*)d_in[6];
    const bf16* g2b   = (const bf16*)d_in[7];
    const bf16* be2b  = (const bf16*)d_in[8];
    bf16* yb = (bf16*)d_out;
    // MODE 1: fp32 tensors
    const float* xf    = (const float*)d_in[0];
    const float* g1f   = (const float*)d_in[1];
    const float* be1f  = (const float*)d_in[2];
    const float* sinf_ = (const float*)d_in[3];
    const float* wbf   = (const float*)d_in[4];
    const float* cbf   = (const float*)d_in[5];
    const float* soutf = (const float*)d_in[6];
    const float* g2f   = (const float*)d_in[7];
    const float* be2f  = (const float*)d_in[8];
    float* yf = (float*)d_out;

    wprep_k<0, bf16> <<<dim3(576), 256, 0, stream>>>(flag, wbb, wfrag);
    wprep_k<1, float><<<dim3(576), 256, 0, stream>>>(flag, wbf, wfrag);

    bn1_k<0, bf16> <<<dim3(CIN, 4), 256, 0, stream>>>(flag, xb, s1, q1);
    bn1_k<1, float><<<dim3(CIN, 4), 256, 0, stream>>>(flag, xf, s1, q1);
    bn1fin_k<0, bf16> <<<1, 128, 0, stream>>>(flag, g1b, be1b, s1, q1, a1, b1);
    bn1fin_k<1, float><<<1, 128, 0, stream>>>(flag, g1f, be1f, s1, q1, a1, b1);

    conv_mfma_k<0, bf16> <<<dim3(TOUT / 4, N_), 256, 0, stream>>>(flag, xb, wfrag, cbb, sinb, a1, b1, yb);
    conv_mfma_k<1, float><<<dim3(TOUT / 4, N_), 256, 0, stream>>>(flag, xf, wfrag, cbf, sinf_, a1, b1, yf);

    bn2_k<0, bf16> <<<dim3(COUT, 4), 256, 0, stream>>>(flag, yb, soutb, s2, q2);
    bn2_k<1, float><<<dim3(COUT, 4), 256, 0, stream>>>(flag, yf, soutf, s2, q2);
    bn2fin_k<0, bf16> <<<1, 256, 0, stream>>>(flag, g2b, be2b, s2, q2, a2, b2);
    bn2fin_k<1, float><<<1, 256, 0, stream>>>(flag, g2f, be2f, s2, q2, a2, b2);

    final_k<0, bf16> <<<dim3(COUT, N_), 256, 0, stream>>>(flag, yb, soutb, a2, b2);
    final_k<1, float><<<dim3(COUT, N_), 256, 0, stream>>>(flag, yf, soutf, a2, b2);
}

// Round 8
// 484.573 us; speedup vs baseline: 2.1952x; 1.0898x over previous
//
#include <hip/hip_runtime.h>
#include <hip/hip_bf16.h>

#define N_    64
#define CIN   128
#define COUT  256
#define T_    128
#define V_    25
#define TOUT  64
#define VOUT  13
#define EPS_  1e-5f
#define CNT1  ((float)(N_ * T_ * V_))
#define CNT2  ((float)(N_ * TOUT * VOUT))

typedef __hip_bfloat16 bf16;
typedef __attribute__((ext_vector_type(8))) short short8x;
typedef __attribute__((ext_vector_type(4))) float f32x4;

__device__ __forceinline__ float ldv(const bf16* p)  { return __bfloat162float(*p); }
__device__ __forceinline__ float ldv(const float* p) { return *p; }
__device__ __forceinline__ void  stv(bf16* p, float v)  { *p = __float2bfloat16(v); }
__device__ __forceinline__ void  stv(float* p, float v) { *p = v; }

__device__ __forceinline__ unsigned bf16rne(float f) {
    unsigned u = __float_as_uint(f);
    return (u + 0x7FFFu + ((u >> 16) & 1u)) >> 16;
}

// non-temporal (streaming) accessors
__device__ __forceinline__ float ldnt(const float* p) { return __builtin_nontemporal_load(p); }
__device__ __forceinline__ float ldnt(const bf16* p) {
    unsigned short u = __builtin_nontemporal_load((const unsigned short*)p);
    return __uint_as_float((unsigned)u << 16);
}
__device__ __forceinline__ void stnt(float* p, float v) { __builtin_nontemporal_store(v, p); }
__device__ __forceinline__ void stnt(bf16* p, float v) {
    unsigned short u = (unsigned short)bf16rne(v);
    __builtin_nontemporal_store(u, (unsigned short*)p);
}

__device__ __forceinline__ void load4(const float* p, float& a, float& b, float& c, float& d) {
    float4 v = *reinterpret_cast<const float4*>(p);
    a = v.x; b = v.y; c = v.z; d = v.w;
}
__device__ __forceinline__ void load4(const bf16* p, float& a, float& b, float& c, float& d) {
    ushort4 u = *reinterpret_cast<const ushort4*>(p);
    a = __uint_as_float((unsigned)u.x << 16);
    b = __uint_as_float((unsigned)u.y << 16);
    c = __uint_as_float((unsigned)u.z << 16);
    d = __uint_as_float((unsigned)u.w << 16);
}

__device__ __forceinline__ void blockReduce2(float& s, float& ss) {
    __shared__ float ls[4], lss[4];
    int lane = threadIdx.x & 63, wid = threadIdx.x >> 6;
#pragma unroll
    for (int o = 32; o > 0; o >>= 1) {
        s  += __shfl_down(s, o, 64);
        ss += __shfl_down(ss, o, 64);
    }
    if (lane == 0) { ls[wid] = s; lss[wid] = ss; }
    __syncthreads();
    if (threadIdx.x == 0) {
        s  = ls[0] + ls[1] + ls[2] + ls[3];
        ss = lss[0] + lss[1] + lss[2] + lss[3];
    }
}

// ---- dtype detector + zero-init of bn partial sums (graph-replay reset) ----
__global__ void detect_k(const unsigned short* __restrict__ xr, int* flag,
                         float* __restrict__ s1, float* __restrict__ q1,
                         float* __restrict__ s2, float* __restrict__ q2) {
    if (threadIdx.x < CIN) { s1[threadIdx.x] = 0.f; q1[threadIdx.x] = 0.f; }
    s2[threadIdx.x] = 0.f; q2[threadIdx.x] = 0.f;
    __shared__ int cnt;
    if (threadIdx.x == 0) cnt = 0;
    __syncthreads();
    int c = 0;
    for (int i = threadIdx.x; i < 8192; i += 256) {
        int e = (xr[i] >> 7) & 0xFF;
        if (e >= 192) c++;
    }
    atomicAdd(&cnt, c);
    __syncthreads();
    if (threadIdx.x == 0) flag[0] = (cnt > 0) ? 1 : 0;
}

// ---- weight prepass: hi/lo bf16 split, MFMA-fragment order, NO k-duplication ----
// frag f = ((tap*2+kind)*16 + ctg)*4 + ch  (ctg = co/16, ch = ci/32, kind 0=hi 1=lo)
// ushort wf[f*512 + lane*8 + j] = w[co = ctg*16+(lane&15)][ci = ch*32+(lane>>4)*8+j][tap]
template<typename DT>
__device__ __forceinline__ void prep_body(const DT* __restrict__ wgt, unsigned short* __restrict__ wf) {
    int gid  = blockIdx.x * 256 + threadIdx.x;    // 0 .. 73727
    int lane = gid & 63;
    int f    = gid >> 6;                          // 0 .. 1151
    int ch   = f & 3;
    int ctg  = (f >> 2) & 15;
    int kind = (f >> 6) & 1;
    int tap  = f >> 7;                            // 0..8
    int co   = ctg * 16 + (lane & 15);
    int cib  = ch * 32 + (lane >> 4) * 8;
    unsigned short o[8];
#pragma unroll
    for (int j = 0; j < 8; j++) {
        float w = ldv(&wgt[((size_t)co * CIN + cib + j) * 9 + tap]);
        unsigned hb = bf16rne(w);
        if (kind == 0) o[j] = (unsigned short)hb;
        else           o[j] = (unsigned short)bf16rne(w - __uint_as_float(hb << 16));
    }
    *reinterpret_cast<ushort4*>(wf + (size_t)gid * 8)     = make_ushort4(o[0], o[1], o[2], o[3]);
    *reinterpret_cast<ushort4*>(wf + (size_t)gid * 8 + 4) = make_ushort4(o[4], o[5], o[6], o[7]);
}
__global__ __launch_bounds__(256) void prep_k(const int* __restrict__ flag,
                                              const void* __restrict__ w, unsigned short* __restrict__ wf) {
    if (flag[0]) prep_body<float>((const float*)w, wf);
    else         prep_body<bf16>((const bf16*)w, wf);
}

// ---- BN1 partial sums ----
template<typename DT>
__device__ __forceinline__ void bn1_body(const DT* __restrict__ x,
                                         float* __restrict__ s1, float* __restrict__ q1) {
    const int c  = blockIdx.x;
    const int n0 = blockIdx.y * (N_ / 4);
    float s = 0.f, ss = 0.f;
    for (int idx = threadIdx.x; idx < (N_ / 4) * 800; idx += 256) {
        int n = n0 + idx / 800;
        int q = idx - (idx / 800) * 800;
        const DT* xp = x + ((size_t)n * CIN + c) * (T_ * V_) + q * 4;
        float v0, v1, v2, v3;
        load4(xp, v0, v1, v2, v3);
        s  += (v0 + v1) + (v2 + v3);
        ss += (v0 * v0 + v1 * v1) + (v2 * v2 + v3 * v3);
    }
    blockReduce2(s, ss);
    if (threadIdx.x == 0) { atomicAdd(&s1[c], s); atomicAdd(&q1[c], ss); }
}
__global__ __launch_bounds__(256) void bn1_k(const int* __restrict__ flag, const void* __restrict__ x,
                                             float* __restrict__ s1, float* __restrict__ q1) {
    if (flag[0]) bn1_body<float>((const float*)x, s1, q1);
    else         bn1_body<bf16>((const bf16*)x, s1, q1);
}

// ================= fused BN1-finalize + shift_in + conv (MFMA 3-product) =================
// Block (tg, n), 4 waves; wave wv owns co [wv*64, +64) (4 ct of 16) x 4 to.
// 4 chunks of 32 ci. LDS: 2 bf16 H-planes [lt 9][vv 27][ci 32 +8pad] (38.9 KB)
// + a1/b1 (1 KB). Per tap: 8 A-frag loads (hi,lo x 4ct, coalesced 1KB each),
// 8 B ds_read_b128 (hi,lo x 4tt), 48 MFMA {wh*hh, wh*hl, wl*hh}.
#define HPLANE (9 * 27 * 40)
template<typename DT>
__device__ __forceinline__ void conv_body(const DT* __restrict__ x, const unsigned short* __restrict__ wf,
                                          const DT* __restrict__ bias, const DT* __restrict__ s_in,
                                          const DT* __restrict__ g1, const DT* __restrict__ be1,
                                          const float* __restrict__ s1, const float* __restrict__ q1,
                                          DT* __restrict__ y,
                                          short* hp, float* a1s, float* b1s) {
    const int tg   = blockIdx.x;      // 0..15
    const int n    = blockIdx.y;      // 0..63
    const int tid  = threadIdx.x;
    const int wv   = tid >> 6;
    const int lane = tid & 63;
    const int khi  = lane >> 4;
    const int ln16 = lane & 15;
    const int tbase = 8 * tg - 1;

    // fold BN1-finalize: a1/b1 into LDS
    if (tid < CIN) {
        float mean = s1[tid] / CNT1;
        float var  = q1[tid] / CNT1 - mean * mean;
        float a = ldv(&g1[tid]) * rsqrtf(var + EPS_);
        a1s[tid] = a;
        b1s[tid] = ldv(&be1[tid]) - mean * a;
    }
    __syncthreads();

    const short8x* wfv = reinterpret_cast<const short8x*>(wf);
    const short8x* shv = reinterpret_cast<const short8x*>(hp);

    f32x4 acc[4][4];
#pragma unroll
    for (int ct = 0; ct < 4; ct++)
#pragma unroll
        for (int tt = 0; tt < 4; tt++) acc[ct][tt] = (f32x4){0.f, 0.f, 0.f, 0.f};

    const int vvt  = tid & 31;        // staging vv (27 used)
    const int ci8  = tid >> 5;        // staging ci low
    const int v_in = vvt - 1;
    const bool vok = (vvt >= 1) && (vvt <= 25);

#pragma unroll 1
    for (int ch = 0; ch < 4; ch++) {
        __syncthreads();              // previous chunk's reads done
        // ---- stage H chunk: div/mod-free indexing ----
        if (vvt < 27) {
#pragma unroll 1
            for (int cq = 0; cq < 4; cq++) {
                const int ci_l = cq * 8 + ci8;
                const int gci  = ch * 32 + ci_l;
                const float sv  = ldv(&s_in[gci]);
                const float a1v = a1s[gci], b1v = b1s[gci];
                const float fs = floorf(sv);
                const float fr = sv - fs;
                const int  ifs = (int)fs;
                const DT* xc = x + ((size_t)n * CIN + gci) * (T_ * V_);
#pragma unroll
                for (int lt = 0; lt < 9; lt++) {
                    const int t_in = tbase + lt;
                    const int i0 = t_in + ifs, i1 = i0 + 1;
                    float w0 = (i0 >= 0 && i0 < T_) ? (1.f - fr) : 0.f;
                    float w1 = (i1 >= 0 && i1 < T_) ? fr : 0.f;
                    float hv = 0.f;
                    if (vok && t_in >= 0 && t_in < T_) {
                        int i0c = min(max(i0, 0), T_ - 1);
                        int i1c = min(max(i1, 0), T_ - 1);
                        float xv = w0 * ldnt(&xc[i0c * V_ + v_in]) + w1 * ldnt(&xc[i1c * V_ + v_in]);
                        hv = a1v * xv + b1v * (w0 + w1);
                    }
                    unsigned hb = bf16rne(hv);
                    unsigned lb = bf16rne(hv - __uint_as_float(hb << 16));
                    int rb = (lt * 27 + vvt) * 40 + ci_l;
                    hp[rb]          = (short)hb;
                    hp[HPLANE + rb] = (short)lb;
                }
            }
        }
        __syncthreads();

        // ---- MFMA: 9 taps x {8 A-loads, 8 B-reads, 48 MFMA} ----
#pragma unroll 1
        for (int kt = 0; kt < 3; kt++) {
#pragma unroll
            for (int kv = 0; kv < 3; kv++) {
                const int tap = kt * 3 + kv;
                const int vvc = min(2 * ln16 + kv, 26);
                short8x ahi[4], alo[4];
#pragma unroll
                for (int ct = 0; ct < 4; ct++) {
                    const int fh = tap * 128 + (wv * 4 + ct) * 4 + ch;   // kind hi
                    ahi[ct] = wfv[(size_t)fh * 64 + lane];
                    alo[ct] = wfv[(size_t)(fh + 64) * 64 + lane];        // kind lo
                }
#pragma unroll
                for (int tt = 0; tt < 4; tt++) {
                    const int lt = 2 * tt + kt;
                    const int rbase = (lt * 27 + vvc) * 5;
                    short8x bh = shv[rbase + khi];
                    short8x bl = shv[9 * 27 * 5 + rbase + khi];
#pragma unroll
                    for (int ct = 0; ct < 4; ct++)
                        acc[ct][tt] = __builtin_amdgcn_mfma_f32_16x16x32_bf16(ahi[ct], bh, acc[ct][tt], 0, 0, 0);
#pragma unroll
                    for (int ct = 0; ct < 4; ct++)
                        acc[ct][tt] = __builtin_amdgcn_mfma_f32_16x16x32_bf16(ahi[ct], bl, acc[ct][tt], 0, 0, 0);
#pragma unroll
                    for (int ct = 0; ct < 4; ct++)
                        acc[ct][tt] = __builtin_amdgcn_mfma_f32_16x16x32_bf16(alo[ct], bh, acc[ct][tt], 0, 0, 0);
                }
            }
        }
    }

    // ---- epilogue: bias + relu + nt store ----
    if (ln16 < VOUT) {
#pragma unroll
        for (int ct = 0; ct < 4; ct++) {
#pragma unroll
            for (int r = 0; r < 4; r++) {
                const int co = wv * 64 + ct * 16 + khi * 4 + r;
                const float bi = ldv(&bias[co]);
#pragma unroll
                for (int tt = 0; tt < 4; tt++) {
                    const int to = tg * 4 + tt;
                    DT* yp = y + (((size_t)n * COUT + co) * TOUT + to) * VOUT;
                    stnt(&yp[ln16], fmaxf(acc[ct][tt][r] + bi, 0.f));
                }
            }
        }
    }
}

__global__ __launch_bounds__(256, 4) void conv_k(const int* __restrict__ flag,
                                                 const void* __restrict__ x, const unsigned short* __restrict__ wf,
                                                 const void* __restrict__ bias, const void* __restrict__ s_in,
                                                 const void* __restrict__ g1, const void* __restrict__ be1,
                                                 const float* __restrict__ s1, const float* __restrict__ q1,
                                                 void* __restrict__ y) {
    __shared__ __align__(16) short hp[2 * HPLANE];
    __shared__ float a1s[CIN], b1s[CIN];
    if (flag[0])
        conv_body<float>((const float*)x, wf, (const float*)bias, (const float*)s_in,
                         (const float*)g1, (const float*)be1, s1, q1, (float*)y, hp, a1s, b1s);
    else
        conv_body<bf16>((const bf16*)x, wf, (const bf16*)bias, (const bf16*)s_in,
                        (const bf16*)g1, (const bf16*)be1, s1, q1, (bf16*)y, hp, a1s, b1s);
}

// ---- BN2 partial sums over z = shift_out(y) ----
template<typename DT>
__device__ __forceinline__ void bn2_body(const DT* __restrict__ y, const DT* __restrict__ s_out,
                                         float* __restrict__ s2, float* __restrict__ q2) {
    int co = blockIdx.x;
    int n0 = blockIdx.y * (N_ / 4);
    float sv = ldv(&s_out[co]);
    float s = 0.f, ss = 0.f;
    for (int i = threadIdx.x; i < (N_ / 4) * TOUT * VOUT; i += 256) {
        int n = n0 + i / (TOUT * VOUT);
        int r = i % (TOUT * VOUT);
        int to = r / VOUT;
        int vo = r % VOUT;
        float tsrc = (float)to + sv;
        float f0 = floorf(tsrc);
        float frac = tsrc - f0;
        int i0 = (int)f0, i1 = i0 + 1;
        float w0 = (i0 >= 0 && i0 < TOUT) ? (1.f - frac) : 0.f;
        float w1 = (i1 >= 0 && i1 < TOUT) ? frac : 0.f;
        int i0c = min(max(i0, 0), TOUT - 1);
        int i1c = min(max(i1, 0), TOUT - 1);
        const DT* yc = y + ((size_t)n * COUT + co) * (TOUT * VOUT);
        float z = w0 * ldv(&yc[i0c * VOUT + vo]) + w1 * ldv(&yc[i1c * VOUT + vo]);
        s += z; ss += z * z;
    }
    blockReduce2(s, ss);
    if (threadIdx.x == 0) { atomicAdd(&s2[co], s); atomicAdd(&q2[co], ss); }
}
__global__ __launch_bounds__(256) void bn2_k(const int* __restrict__ flag, const void* __restrict__ y,
                                             const void* __restrict__ s_out,
                                             float* __restrict__ s2, float* __restrict__ q2) {
    if (flag[0]) bn2_body<float>((const float*)y, (const float*)s_out, s2, q2);
    else         bn2_body<bf16>((const bf16*)y, (const bf16*)s_out, s2, q2);
}

// ---- fused BN2-finalize + in-place out = a2*shift_out(y) + b2 ----
template<typename DT>
__device__ __forceinline__ void final_body(DT* __restrict__ y, const DT* __restrict__ s_out,
                                           const DT* __restrict__ g2, const DT* __restrict__ be2,
                                           const float* __restrict__ s2, const float* __restrict__ q2,
                                           float* pl, float* ab) {
    int co = blockIdx.x, n = blockIdx.y;
    DT* base = y + ((size_t)n * COUT + co) * (TOUT * VOUT);
    if (threadIdx.x == 0) {
        float mean = s2[co] / CNT2;
        float var  = q2[co] / CNT2 - mean * mean;
        float a = ldv(&g2[co]) * rsqrtf(var + EPS_);
        ab[0] = a;
        ab[1] = ldv(&be2[co]) - mean * a;
    }
    for (int i = threadIdx.x; i < TOUT * VOUT; i += 256) pl[i] = ldv(&base[i]);
    __syncthreads();
    float sv = ldv(&s_out[co]);
    float A = ab[0], B = ab[1];
    for (int i = threadIdx.x; i < TOUT * VOUT; i += 256) {
        int to = i / VOUT, vo = i % VOUT;
        float tsrc = (float)to + sv;
        float f0 = floorf(tsrc);
        float frac = tsrc - f0;
        int i0 = (int)f0, i1 = i0 + 1;
        float w0 = (i0 >= 0 && i0 < TOUT) ? (1.f - frac) : 0.f;
        float w1 = (i1 >= 0 && i1 < TOUT) ? frac : 0.f;
        int i0c = min(max(i0, 0), TOUT - 1);
        int i1c = min(max(i1, 0), TOUT - 1);
        float z = w0 * pl[i0c * VOUT + vo] + w1 * pl[i1c * VOUT + vo];
        stv(&base[i], A * z + B);
    }
}
__global__ __launch_bounds__(256) void final_k(const int* __restrict__ flag, void* __restrict__ y,
                                               const void* __restrict__ s_out,
                                               const void* __restrict__ g2, const void* __restrict__ be2,
                                               const float* __restrict__ s2, const float* __restrict__ q2) {
    __shared__ float pl[TOUT * VOUT];
    __shared__ float ab[2];
    if (flag[0]) final_body<float>((float*)y, (const float*)s_out, (const float*)g2, (const float*)be2, s2, q2, pl, ab);
    else         final_body<bf16>((bf16*)y, (const bf16*)s_out, (const bf16*)g2, (const bf16*)be2, s2, q2, pl, ab);
}

extern "C" void kernel_launch(void* const* d_in, const int* in_sizes, int n_in,
                              void* d_out, int out_size, void* d_ws, size_t ws_size,
                              hipStream_t stream) {
    // ws: flag@0 | s1@256 (128f) | q1@768 | s2@1280 (256f) | q2@2304 | wf@8192 (1.15 MB ushort)
    int*   flag = (int*)d_ws;
    float* s1 = (float*)((char*)d_ws + 256);
    float* q1 = s1 + 128;
    float* s2 = q1 + 128;
    float* q2 = s2 + 256;
    unsigned short* wf = (unsigned short*)((char*)d_ws + 8192);

    detect_k<<<1, 256, 0, stream>>>((const unsigned short*)d_in[0], flag, s1, q1, s2, q2);
    prep_k  <<<dim3(288), 256, 0, stream>>>(flag, d_in[4], wf);
    bn1_k   <<<dim3(CIN, 4), 256, 0, stream>>>(flag, d_in[0], s1, q1);
    conv_k  <<<dim3(TOUT / 4, N_), 256, 0, stream>>>(flag, d_in[0], wf, d_in[5], d_in[3],
                                                     d_in[1], d_in[2], s1, q1, d_out);
    bn2_k   <<<dim3(COUT, 4), 256, 0, stream>>>(flag, d_out, d_in[6], s2, q2);
    final_k <<<dim3(COUT, N_), 256, 0, stream>>>(flag, d_out, d_in[6], d_in[7], d_in[8], s2, q2);
}